// Round 10
// baseline (176.346 us; speedup 1.0000x reference)
//
#include <hip/hip_runtime.h>

#define DIN 128
#define BINW 128        // nodes per bin
#define BINSHIFT 7
#define NB_MAX 1024     // supports n <= 131072
#define CHUNK 4096      // edges per binning block (r10: halved for occupancy)

// ---------------------------------------------------------------------------
// out = round(clip( A^2 q + c1*(A 1) + c0 , 0, 10)),  A = D^-1/2 (W+I) D^-1/2
// q = X w1f; w2f = W2@fcw, w1f = W1@w2f, c1 = b1·w2f, c0 = b2·fcw + fcb.
// Factored:  t = A q + c1·1 ;  u = A t + c0.   v1 = dis*q, v2 = dis*t (8B f64).
//
// Scattered-op cost model v5 (rounds 0-9): per-edge global scattered ATOMICS
// ~20 G/s chip wall (invariant to padding r2, per-thread MLP r3). Scattered
// plain reads: LATENCY x WAVE-CONCURRENCY bound -- per-thread ILP null (r7),
// wave doubling 12->24/CU gave -17us (r9). This round: both starved kernels
// to the 32-wave/CU cap (spmv 1024-thr blocks; binscatter CHUNK 4096).
//   K1 prep:      w1f, c0, c1
//   K2 hist+gemv: LDS hist of dst>>7 per chunk -> histT (int4 loads)
//                 (+ q = X w1f, float4: 2 rows/wave)
//   K3 binscan:   wave/bin exscan histT over chunks -> chunkOfsT; binCnt
//   K4 scan:      binBase = exscan(binCnt)
//   K5 binscatter: single-pass placement, zero global atomics (int4 loads)
//   K6 setup:     per bin: wsum (LDS f32) -> dis; v1=dis*q; tpart=c1+dis^2 q
//   K7 spmv1:     1024 thr, 8 sub-accs: acc += ew*v1[s]; v2=dis*(tpart+dis*S)
//   K8 spmv2:     same with v2 gather; u=c0+dis*(v2+S); out=round(clip)
// ---------------------------------------------------------------------------

__global__ void precompute_kernel(const float* __restrict__ W1, const float* __restrict__ b1,
                                  const float* __restrict__ W2, const float* __restrict__ b2,
                                  const float* __restrict__ fcw, const float* __restrict__ fcb,
                                  double* __restrict__ w1f, double* __restrict__ cvals) {
    const int t = threadIdx.x;
    __shared__ double sw2f[64];
    if (t < 64) {
        double s = 0.0;
        for (int j = 0; j < 64; j++) s += (double)W2[t * 64 + j] * (double)fcw[j];
        sw2f[t] = s;
    }
    __syncthreads();
    if (t < 128) {
        double s = 0.0;
        for (int j = 0; j < 64; j++) s += (double)W1[t * 64 + j] * sw2f[j];
        w1f[t] = s;
    }
    if (t == 128) {
        double c1 = 0.0, c0 = (double)fcb[0];
        for (int j = 0; j < 64; j++) {
            c1 += (double)b1[j] * sw2f[j];
            c0 += (double)b2[j] * (double)fcw[j];
        }
        cvals[0] = c0;
        cvals[1] = c1;
    }
}

// blocks [0,hblk): LDS histogram of CHUNK edges (int4 loads) -> histT[c][b].
// blocks [hblk,..): gemv q = X w1f, float4 loads, 2 rows per 64-lane wave.
__global__ __launch_bounds__(256) void hist_gemv_kernel(
        const int* __restrict__ dst, const float* __restrict__ X,
        const double* __restrict__ w1f, unsigned* __restrict__ histT,
        double* __restrict__ q, int n, int e, int nb, int hblk) {
    __shared__ unsigned cnt[NB_MAX];
    const int blk = blockIdx.x;
    const int t = threadIdx.x;
    if (blk < hblk) {
        for (int b = t; b < nb; b += 256) cnt[b] = 0u;
        __syncthreads();
        const long base = (long)blk * CHUNK;
#pragma unroll
        for (int k = 0; k < CHUNK / 1024; k++) {           // 4 iters of int4
            long i = base + ((long)k * 256 + t) * 4;
            if (i + 3 < e) {
                int4 d4 = *(const int4*)(dst + i);
                atomicAdd(&cnt[d4.x >> BINSHIFT], 1u);
                atomicAdd(&cnt[d4.y >> BINSHIFT], 1u);
                atomicAdd(&cnt[d4.z >> BINSHIFT], 1u);
                atomicAdd(&cnt[d4.w >> BINSHIFT], 1u);
            } else {
                for (int j = 0; j < 4; j++)
                    if (i + j < e) atomicAdd(&cnt[dst[i + j] >> BINSHIFT], 1u);
            }
        }
        __syncthreads();
        for (int b = t; b < nb; b += 256)
            histT[(long)blk * nb + b] = cnt[b];            // coalesced
        return;
    }
    long g = (long)(blk - hblk) * 256 + t;
    int w = (int)(g >> 6);         // global wave index
    int lane = (int)(g & 63);
    int sub = lane >> 5;           // 2 rows per wave
    int l = lane & 31;
    int row = w * 2 + sub;
    if (row >= n) return;
    float4 x = *(const float4*)(X + (long)row * DIN + 4 * l);  // 1KB/wave coalesced
    double v = (double)x.x * w1f[4 * l] + (double)x.y * w1f[4 * l + 1]
             + (double)x.z * w1f[4 * l + 2] + (double)x.w * w1f[4 * l + 3];
#pragma unroll
    for (int off = 16; off > 0; off >>= 1) v += __shfl_down(v, off, 64);
    if (l == 0) q[row] = v;
}

// one wave per bin: exclusive scan of histT[c][b] over chunks c ->
// chunkOfsT[c][b]; binCnt[b] = bin total. Scattered 4B ops, L2-resident.
__global__ __launch_bounds__(256) void binscan_kernel(
        const unsigned* __restrict__ histT, unsigned* __restrict__ chunkOfsT,
        unsigned* __restrict__ binCnt, int nb, int hblk) {
    int gw = (int)((blockIdx.x * 256 + threadIdx.x) >> 6);  // wave = bin
    int l = threadIdx.x & 63;
    if (gw >= nb) return;
    unsigned carry = 0u;
    for (int c0 = 0; c0 < hblk; c0 += 64) {
        int c = c0 + l;
        unsigned v = (c < hblk) ? histT[(long)c * nb + gw] : 0u;
        unsigned s = v;
#pragma unroll
        for (int off = 1; off < 64; off <<= 1) {
            unsigned u = __shfl_up(s, off, 64);
            if (l >= off) s += u;
        }
        if (c < hblk) chunkOfsT[(long)c * nb + gw] = carry + s - v;
        carry += (unsigned)__shfl((int)s, 63, 64);
    }
    if (l == 0) binCnt[gw] = carry;
}

// 1 block: exclusive scan of binCnt[nb] -> binBase[nb+1]
__global__ void scan_kernel(const unsigned* __restrict__ binCnt,
                            unsigned* __restrict__ binBase, int nb) {
    __shared__ unsigned part[256];
    const int t = threadIdx.x;
    unsigned loc[4];
    unsigned s = 0;
#pragma unroll
    for (int k = 0; k < 4; k++) {
        int idx = t * 4 + k;
        unsigned v = (idx < nb) ? binCnt[idx] : 0u;
        loc[k] = s;
        s += v;
    }
    part[t] = s;
    __syncthreads();
    if (t == 0) {
        unsigned run = 0;
        for (int j = 0; j < 256; j++) { unsigned v = part[j]; part[j] = run; run += v; }
    }
    __syncthreads();
    unsigned p = part[t];
#pragma unroll
    for (int k = 0; k < 4; k++) {
        int idx = t * 4 + k;
        if (idx < nb) binBase[idx] = p + loc[k];
    }
    if (t == 255) binBase[nb] = p + s;
}

// single-pass placement, zero global atomics: sbase from binBase+chunkOfsT
// (coalesced), local order via LDS atomic, scattered 8B store. CHUNK=4096 ->
// 391 blocks x 16 waves: all CUs busy (was 196 blocks = 60 CUs idle).
__global__ __launch_bounds__(1024) void binscatter_kernel(
        const int* __restrict__ src, const int* __restrict__ dst,
        const float* __restrict__ ew, const unsigned* __restrict__ binBase,
        const unsigned* __restrict__ chunkOfsT,
        uint2* __restrict__ binned, int e, int nb) {
    __shared__ unsigned cnt[NB_MAX];
    __shared__ unsigned sbase[NB_MAX];
    const int c = blockIdx.x;
    const int t = threadIdx.x;
    for (int b = t; b < nb; b += 1024) {
        cnt[b] = 0u;
        sbase[b] = binBase[b] + chunkOfsT[(long)c * nb + b];  // coalesced
    }
    __syncthreads();
    const long base = (long)c * CHUNK;
    {
        long i = base + (long)t * 4;                       // 1024 thr x int4 = 4096
        if (i + 3 < e) {
            int4 d4 = *(const int4*)(dst + i);
            int4 s4 = *(const int4*)(src + i);
            float4 w4 = *(const float4*)(ew + i);
            int dd[4] = {d4.x, d4.y, d4.z, d4.w};
            int ss[4] = {s4.x, s4.y, s4.z, s4.w};
            float ww[4] = {w4.x, w4.y, w4.z, w4.w};
#pragma unroll
            for (int j = 0; j < 4; j++) {
                int b = dd[j] >> BINSHIFT;
                unsigned p = sbase[b] + atomicAdd(&cnt[b], 1u);
                binned[p] = uint2{(unsigned)ss[j] | ((unsigned)(dd[j] & (BINW - 1)) << 20),
                                  __float_as_uint(ww[j])};
            }
        } else {
            for (int j = 0; j < 4; j++) {
                long i2 = i + j;
                if (i2 < e) {
                    int d = dst[i2];
                    int b = d >> BINSHIFT;
                    unsigned p = sbase[b] + atomicAdd(&cnt[b], 1u);
                    binned[p] = uint2{(unsigned)src[i2] | ((unsigned)(d & (BINW - 1)) << 20),
                                      __float_as_uint(ew[i2])};
                }
            }
        }
    }
}

// per bin: wsum[dlow] += ew (LDS f32 atomics) -> dis; disA = dis;
// v1 = dis*q; tpart = c1 + dis^2 q
__global__ __launch_bounds__(256) void setup_kernel(
        const uint2* __restrict__ binned, const unsigned* __restrict__ binBase,
        const double* __restrict__ cvals, const double* __restrict__ q,
        float* __restrict__ disA, double* __restrict__ v1,
        double* __restrict__ tpart, int n) {
    __shared__ float ws[BINW];
    const int b = blockIdx.x;
    const int t = threadIdx.x;
    if (t < BINW) ws[t] = 0.0f;
    __syncthreads();
    const unsigned s0 = binBase[b], s1 = binBase[b + 1];
    for (unsigned i = s0 + t; i < s1; i += 256) {
        uint2 v = binned[i];
        atomicAdd(&ws[v.x >> 20], __uint_as_float(v.y));
    }
    __syncthreads();
    if (t < BINW) {
        int node = b * BINW + t;
        if (node < n) {
            float d = 1.0f + ws[t];  // self-loop weight 1
            float di = (d > 0.0f) ? (1.0f / sqrtf(fmaxf(d, 1e-12f))) : 0.0f;
            double qv = q[node];
            disA[node] = di;
            v1[node] = (double)di * qv;
            tpart[node] = cvals[1] + (double)(di * di) * qv;
        }
    }
}

// 1024-thr block per bin (16 waves; 2 blocks/CU resident = 32 waves/CU, the
// hardware cap). 8 LDS sub-accumulators kill contention.
// acc[sub][dlow] += ew * v1[s]; epilogue: v2 = dis*(tpart + dis*S)
__global__ __launch_bounds__(1024) void spmv1_kernel(
        const uint2* __restrict__ binned, const unsigned* __restrict__ binBase,
        const double* __restrict__ v1, const float* __restrict__ disA,
        const double* __restrict__ tpart, double* __restrict__ v2, int n) {
    __shared__ double acc[8][BINW];
    const int b = blockIdx.x;
    const int t = threadIdx.x;
    const int sub = t >> 7;
    {
        double* f = &acc[0][0];
        f[t] = 0.0;  // 8*128 = 1024 doubles
    }
    __syncthreads();
    const unsigned s0 = binBase[b], s1 = binBase[b + 1];
    for (unsigned tile = s0; tile < s1; tile += 4096) {
        uint2 ee[4];
        double vv[4];
        bool ok[4];
#pragma unroll
        for (int k = 0; k < 4; k++) {
            unsigned idx = tile + t + k * 1024u;
            ok[k] = (idx < s1);
            if (ok[k]) ee[k] = binned[idx];             // coalesced 8B
        }
#pragma unroll
        for (int k = 0; k < 4; k++)
            if (ok[k]) vv[k] = v1[ee[k].x & 0xFFFFFu];  // scattered 8B gather
#pragma unroll
        for (int k = 0; k < 4; k++)
            if (ok[k])
                atomicAdd(&acc[sub][ee[k].x >> 20],
                          (double)__uint_as_float(ee[k].y) * vv[k]);
    }
    __syncthreads();
    if (t < BINW) {
        int node = b * BINW + t;
        if (node < n) {
            double S = 0.0;
#pragma unroll
            for (int g = 0; g < 8; g++) S += acc[g][t];
            double di = (double)disA[node];
            v2[node] = di * (tpart[node] + di * S);
        }
    }
}

// same structure: acc[sub][dlow] += ew * v2[s]; u = c0 + dis*(v2 + S)
__global__ __launch_bounds__(1024) void spmv2_head_kernel(
        const uint2* __restrict__ binned, const unsigned* __restrict__ binBase,
        const double* __restrict__ v2, const float* __restrict__ disA,
        const double* __restrict__ cvals, float* __restrict__ out, int n) {
    __shared__ double acc[8][BINW];
    const int b = blockIdx.x;
    const int t = threadIdx.x;
    const int sub = t >> 7;
    {
        double* f = &acc[0][0];
        f[t] = 0.0;
    }
    __syncthreads();
    const unsigned s0 = binBase[b], s1 = binBase[b + 1];
    for (unsigned tile = s0; tile < s1; tile += 4096) {
        uint2 ee[4];
        double vv[4];
        bool ok[4];
#pragma unroll
        for (int k = 0; k < 4; k++) {
            unsigned idx = tile + t + k * 1024u;
            ok[k] = (idx < s1);
            if (ok[k]) ee[k] = binned[idx];
        }
#pragma unroll
        for (int k = 0; k < 4; k++)
            if (ok[k]) vv[k] = v2[ee[k].x & 0xFFFFFu];
#pragma unroll
        for (int k = 0; k < 4; k++)
            if (ok[k])
                atomicAdd(&acc[sub][ee[k].x >> 20],
                          (double)__uint_as_float(ee[k].y) * vv[k]);
    }
    __syncthreads();
    if (t < BINW) {
        int node = b * BINW + t;
        if (node < n) {
            double S = 0.0;
#pragma unroll
            for (int g = 0; g < 8; g++) S += acc[g][t];
            double u = cvals[0] + (double)disA[node] * (v2[node] + S);
            float o = (float)u;
            o = fminf(fmaxf(o, 0.0f), 10.0f);
            out[node] = rintf(o);  // v_rndne_f32: half-to-even, matches jnp.round
        }
    }
}

extern "C" void kernel_launch(void* const* d_in, const int* in_sizes, int n_in,
                              void* d_out, int out_size, void* d_ws, size_t ws_size,
                              hipStream_t stream) {
    const float* x   = (const float*)d_in[0];  // [N, 128]
    const int*   eix = (const int*)d_in[1];    // [2, E]
    const float* ew  = (const float*)d_in[2];  // [E]
    const float* W1  = (const float*)d_in[3];  // [128, 64]
    const float* b1  = (const float*)d_in[4];  // [64]
    const float* W2  = (const float*)d_in[5];  // [64, 64]
    const float* b2  = (const float*)d_in[6];  // [64]
    const float* fcw = (const float*)d_in[7];  // [64]
    const float* fcb = (const float*)d_in[8];  // [1]
    float* out = (float*)d_out;                // [N]

    const int n = in_sizes[0] / DIN;
    const int e = in_sizes[2];
    const int* src = eix;
    const int* dst = eix + e;
    const int nb = (n + BINW - 1) / BINW;            // 782 bins at n=100000
    const int hblk = (e + CHUNK - 1) / CHUNK;        // 391 chunks

    // workspace layout (8-byte units, 64-unit aligned regions); ~19 MB
    auto al = [](size_t v) { return (v + 63) & ~(size_t)63; };
    double* ws = (double*)d_ws;
    size_t o = 0;
    double*   w1f     = ws + o; o += al(DIN);
    double*   cvals   = ws + o; o += al(2);
    double*   q       = ws + o; o += al((size_t)n);
    double*   tpart   = ws + o; o += al((size_t)n);
    double*   v1      = ws + o; o += al((size_t)n);
    double*   v2      = ws + o; o += al((size_t)n);
    float*    disA    = (float*)(ws + o);    o += al(((size_t)n + 1) / 2);
    unsigned* binCnt  = (unsigned*)(ws + o); o += al(((size_t)nb + 1) / 2);
    unsigned* binBase = (unsigned*)(ws + o); o += al(((size_t)nb + 2) / 2);
    unsigned* histT   = (unsigned*)(ws + o); o += al(((size_t)nb * hblk + 1) / 2);
    unsigned* chunkOfsT = (unsigned*)(ws + o); o += al(((size_t)nb * hblk + 1) / 2);
    uint2*    binned  = (uint2*)(ws + o);   // e * 8B = 12.8 MB

    const int gemvblk = (n + 7) / 8;                 // 2 rows/wave, 4 waves/block
    const int bsblk = (nb * 64 + 255) / 256;         // binscan: wave per bin

    precompute_kernel<<<1, 256, 0, stream>>>(W1, b1, W2, b2, fcw, fcb, w1f, cvals);
    hist_gemv_kernel<<<hblk + gemvblk, 256, 0, stream>>>(dst, x, w1f, histT,
                                                         q, n, e, nb, hblk);
    binscan_kernel<<<bsblk, 256, 0, stream>>>(histT, chunkOfsT, binCnt, nb, hblk);
    scan_kernel<<<1, 256, 0, stream>>>(binCnt, binBase, nb);
    binscatter_kernel<<<hblk, 1024, 0, stream>>>(src, dst, ew, binBase, chunkOfsT,
                                                 binned, e, nb);
    setup_kernel<<<nb, 256, 0, stream>>>(binned, binBase, cvals, q, disA, v1,
                                         tpart, n);
    spmv1_kernel<<<nb, 1024, 0, stream>>>(binned, binBase, v1, disA, tpart, v2, n);
    spmv2_head_kernel<<<nb, 1024, 0, stream>>>(binned, binBase, v2, disA, cvals,
                                               out, n);
}

// Round 11
// 173.981 us; speedup vs baseline: 1.0136x; 1.0136x over previous
//
#include <hip/hip_runtime.h>

#define DIN 128
#define BINW 128        // nodes per bin
#define BINSHIFT 7
#define NB_MAX 1024     // supports n <= 131072
#define CHUNK 8192      // edges per binning block (r9 best config)

// ---------------------------------------------------------------------------
// out = round(clip( A^2 q + c1*(A 1) + c0 , 0, 10)),  A = D^-1/2 (W+I) D^-1/2
// q = X w1f; w2f = W2@fcw, w1f = W1@w2f, c1 = b1·w2f, c0 = b2·fcw + fcb.
// Factored:  t = A q + c1·1 ;  u = A t + c0.   v1 = dis*q, v2 = dis*t (8B f64).
//
// Scattered-op cost model v5 (final, rounds 0-10):
//  - per-edge global scattered ATOMICS: ~20 G/s chip wall (invariant to
//    address padding r2 and per-thread MLP r3) -> designed out entirely via
//    2-level counting sort (per-(chunk,bin) atomics only).
//  - scattered plain L2 gathers: latency x wave-concurrency bound; per-thread
//    ILP null (r7), width null (r7), saturates at ~24 waves/CU (r9; 32 null
//    r10) -> ~58 G/s = the spmv floor (~55us for both passes).
//  - This config (r9) benched 173.8us; r10's 32-wave/8-subacc variant 176.3.
// Structure:
//   K1 prep:      w1f, c0, c1
//   K2 hist+gemv: LDS hist of dst>>7 per chunk -> histT (int4 loads)
//                 (+ q = X w1f, float4: 2 rows/wave)
//   K3 binscan:   wave/bin exscan histT over chunks -> chunkOfsT; binCnt
//   K4 scan:      binBase = exscan(binCnt)
//   K5 binscatter: single-pass placement, zero global atomics (int4 loads)
//   K6 setup:     per bin: wsum (LDS f32) -> dis; v1=dis*q; tpart=c1+dis^2 q
//   K7 spmv1:     512 thr: acc[sub][dlow] += ew*v1[s]; v2=dis*(tpart+dis*sum)
//   K8 spmv2:     same with v2 gather; u=c0+dis*(v2+sum); out=round(clip)
// ---------------------------------------------------------------------------

__global__ void precompute_kernel(const float* __restrict__ W1, const float* __restrict__ b1,
                                  const float* __restrict__ W2, const float* __restrict__ b2,
                                  const float* __restrict__ fcw, const float* __restrict__ fcb,
                                  double* __restrict__ w1f, double* __restrict__ cvals) {
    const int t = threadIdx.x;
    __shared__ double sw2f[64];
    if (t < 64) {
        double s = 0.0;
        for (int j = 0; j < 64; j++) s += (double)W2[t * 64 + j] * (double)fcw[j];
        sw2f[t] = s;
    }
    __syncthreads();
    if (t < 128) {
        double s = 0.0;
        for (int j = 0; j < 64; j++) s += (double)W1[t * 64 + j] * sw2f[j];
        w1f[t] = s;
    }
    if (t == 128) {
        double c1 = 0.0, c0 = (double)fcb[0];
        for (int j = 0; j < 64; j++) {
            c1 += (double)b1[j] * sw2f[j];
            c0 += (double)b2[j] * (double)fcw[j];
        }
        cvals[0] = c0;
        cvals[1] = c1;
    }
}

// blocks [0,hblk): LDS histogram of CHUNK edges (int4 loads) -> histT[c][b].
// blocks [hblk,..): gemv q = X w1f, float4 loads, 2 rows per 64-lane wave.
__global__ __launch_bounds__(256) void hist_gemv_kernel(
        const int* __restrict__ dst, const float* __restrict__ X,
        const double* __restrict__ w1f, unsigned* __restrict__ histT,
        double* __restrict__ q, int n, int e, int nb, int hblk) {
    __shared__ unsigned cnt[NB_MAX];
    const int blk = blockIdx.x;
    const int t = threadIdx.x;
    if (blk < hblk) {
        for (int b = t; b < nb; b += 256) cnt[b] = 0u;
        __syncthreads();
        const long base = (long)blk * CHUNK;
#pragma unroll
        for (int k = 0; k < CHUNK / 1024; k++) {           // 8 iters of int4
            long i = base + ((long)k * 256 + t) * 4;
            if (i + 3 < e) {
                int4 d4 = *(const int4*)(dst + i);
                atomicAdd(&cnt[d4.x >> BINSHIFT], 1u);
                atomicAdd(&cnt[d4.y >> BINSHIFT], 1u);
                atomicAdd(&cnt[d4.z >> BINSHIFT], 1u);
                atomicAdd(&cnt[d4.w >> BINSHIFT], 1u);
            } else {
                for (int j = 0; j < 4; j++)
                    if (i + j < e) atomicAdd(&cnt[dst[i + j] >> BINSHIFT], 1u);
            }
        }
        __syncthreads();
        for (int b = t; b < nb; b += 256)
            histT[(long)blk * nb + b] = cnt[b];            // coalesced
        return;
    }
    long g = (long)(blk - hblk) * 256 + t;
    int w = (int)(g >> 6);         // global wave index
    int lane = (int)(g & 63);
    int sub = lane >> 5;           // 2 rows per wave
    int l = lane & 31;
    int row = w * 2 + sub;
    if (row >= n) return;
    float4 x = *(const float4*)(X + (long)row * DIN + 4 * l);  // 1KB/wave coalesced
    double v = (double)x.x * w1f[4 * l] + (double)x.y * w1f[4 * l + 1]
             + (double)x.z * w1f[4 * l + 2] + (double)x.w * w1f[4 * l + 3];
#pragma unroll
    for (int off = 16; off > 0; off >>= 1) v += __shfl_down(v, off, 64);
    if (l == 0) q[row] = v;
}

// one wave per bin: exclusive scan of histT[c][b] over chunks c ->
// chunkOfsT[c][b]; binCnt[b] = bin total. Scattered 4B ops, L2-resident.
__global__ __launch_bounds__(256) void binscan_kernel(
        const unsigned* __restrict__ histT, unsigned* __restrict__ chunkOfsT,
        unsigned* __restrict__ binCnt, int nb, int hblk) {
    int gw = (int)((blockIdx.x * 256 + threadIdx.x) >> 6);  // wave = bin
    int l = threadIdx.x & 63;
    if (gw >= nb) return;
    unsigned carry = 0u;
    for (int c0 = 0; c0 < hblk; c0 += 64) {
        int c = c0 + l;
        unsigned v = (c < hblk) ? histT[(long)c * nb + gw] : 0u;
        unsigned s = v;
#pragma unroll
        for (int off = 1; off < 64; off <<= 1) {
            unsigned u = __shfl_up(s, off, 64);
            if (l >= off) s += u;
        }
        if (c < hblk) chunkOfsT[(long)c * nb + gw] = carry + s - v;
        carry += (unsigned)__shfl((int)s, 63, 64);
    }
    if (l == 0) binCnt[gw] = carry;
}

// 1 block: exclusive scan of binCnt[nb] -> binBase[nb+1]
__global__ void scan_kernel(const unsigned* __restrict__ binCnt,
                            unsigned* __restrict__ binBase, int nb) {
    __shared__ unsigned part[256];
    const int t = threadIdx.x;
    unsigned loc[4];
    unsigned s = 0;
#pragma unroll
    for (int k = 0; k < 4; k++) {
        int idx = t * 4 + k;
        unsigned v = (idx < nb) ? binCnt[idx] : 0u;
        loc[k] = s;
        s += v;
    }
    part[t] = s;
    __syncthreads();
    if (t == 0) {
        unsigned run = 0;
        for (int j = 0; j < 256; j++) { unsigned v = part[j]; part[j] = run; run += v; }
    }
    __syncthreads();
    unsigned p = part[t];
#pragma unroll
    for (int k = 0; k < 4; k++) {
        int idx = t * 4 + k;
        if (idx < nb) binBase[idx] = p + loc[k];
    }
    if (t == 255) binBase[nb] = p + s;
}

// single-pass placement, zero global atomics: sbase from binBase+chunkOfsT
// (coalesced), local order via LDS atomic, scattered 8B store (run-local
// frontier ~84B/bin). int4/float4 edge loads.
__global__ __launch_bounds__(1024) void binscatter_kernel(
        const int* __restrict__ src, const int* __restrict__ dst,
        const float* __restrict__ ew, const unsigned* __restrict__ binBase,
        const unsigned* __restrict__ chunkOfsT,
        uint2* __restrict__ binned, int e, int nb) {
    __shared__ unsigned cnt[NB_MAX];
    __shared__ unsigned sbase[NB_MAX];
    const int c = blockIdx.x;
    const int t = threadIdx.x;
    for (int b = t; b < nb; b += 1024) {
        cnt[b] = 0u;
        sbase[b] = binBase[b] + chunkOfsT[(long)c * nb + b];  // coalesced
    }
    __syncthreads();
    const long base = (long)c * CHUNK;
#pragma unroll
    for (int k = 0; k < CHUNK / 4096; k++) {               // 2 iters of int4
        long i = base + ((long)k * 1024 + t) * 4;
        if (i + 3 < e) {
            int4 d4 = *(const int4*)(dst + i);
            int4 s4 = *(const int4*)(src + i);
            float4 w4 = *(const float4*)(ew + i);
            int dd[4] = {d4.x, d4.y, d4.z, d4.w};
            int ss[4] = {s4.x, s4.y, s4.z, s4.w};
            float ww[4] = {w4.x, w4.y, w4.z, w4.w};
#pragma unroll
            for (int j = 0; j < 4; j++) {
                int b = dd[j] >> BINSHIFT;
                unsigned p = sbase[b] + atomicAdd(&cnt[b], 1u);
                binned[p] = uint2{(unsigned)ss[j] | ((unsigned)(dd[j] & (BINW - 1)) << 20),
                                  __float_as_uint(ww[j])};
            }
        } else {
            for (int j = 0; j < 4; j++) {
                long i2 = i + j;
                if (i2 < e) {
                    int d = dst[i2];
                    int b = d >> BINSHIFT;
                    unsigned p = sbase[b] + atomicAdd(&cnt[b], 1u);
                    binned[p] = uint2{(unsigned)src[i2] | ((unsigned)(d & (BINW - 1)) << 20),
                                      __float_as_uint(ew[i2])};
                }
            }
        }
    }
}

// per bin: wsum[dlow] += ew (LDS f32 atomics) -> dis; disA = dis;
// v1 = dis*q; tpart = c1 + dis^2 q
__global__ __launch_bounds__(256) void setup_kernel(
        const uint2* __restrict__ binned, const unsigned* __restrict__ binBase,
        const double* __restrict__ cvals, const double* __restrict__ q,
        float* __restrict__ disA, double* __restrict__ v1,
        double* __restrict__ tpart, int n) {
    __shared__ float ws[BINW];
    const int b = blockIdx.x;
    const int t = threadIdx.x;
    if (t < BINW) ws[t] = 0.0f;
    __syncthreads();
    const unsigned s0 = binBase[b], s1 = binBase[b + 1];
    for (unsigned i = s0 + t; i < s1; i += 256) {
        uint2 v = binned[i];
        atomicAdd(&ws[v.x >> 20], __uint_as_float(v.y));
    }
    __syncthreads();
    if (t < BINW) {
        int node = b * BINW + t;
        if (node < n) {
            float d = 1.0f + ws[t];  // self-loop weight 1
            float di = (d > 0.0f) ? (1.0f / sqrtf(fmaxf(d, 1e-12f))) : 0.0f;
            double qv = q[node];
            disA[node] = di;
            v1[node] = (double)di * qv;
            tpart[node] = cvals[1] + (double)(di * di) * qv;
        }
    }
}

// 512-thr block per bin: 4 LDS sub-accumulators (per 128-thr group) kill
// contention; 8 waves/block = 24 waves/CU (the measured gather saturation
// point, r9; 32 waves/CU was null, r10).
// acc[sub][dlow] += ew * v1[s]; epilogue combines subs: v2 = dis*(tpart+dis*S)
__global__ __launch_bounds__(512) void spmv1_kernel(
        const uint2* __restrict__ binned, const unsigned* __restrict__ binBase,
        const double* __restrict__ v1, const float* __restrict__ disA,
        const double* __restrict__ tpart, double* __restrict__ v2, int n) {
    __shared__ double acc[4][BINW];
    const int b = blockIdx.x;
    const int t = threadIdx.x;
    const int sub = t >> 7;
    {
        double* f = &acc[0][0];
        if (t < 512) f[t] = 0.0;  // 4*128 = 512 doubles
    }
    __syncthreads();
    const unsigned s0 = binBase[b], s1 = binBase[b + 1];
    for (unsigned tile = s0; tile < s1; tile += 2048) {
        uint2 ee[4];
        double vv[4];
        bool ok[4];
#pragma unroll
        for (int k = 0; k < 4; k++) {
            unsigned idx = tile + t + k * 512u;
            ok[k] = (idx < s1);
            if (ok[k]) ee[k] = binned[idx];             // coalesced 8B
        }
#pragma unroll
        for (int k = 0; k < 4; k++)
            if (ok[k]) vv[k] = v1[ee[k].x & 0xFFFFFu];  // scattered 8B gather
#pragma unroll
        for (int k = 0; k < 4; k++)
            if (ok[k])
                atomicAdd(&acc[sub][ee[k].x >> 20],
                          (double)__uint_as_float(ee[k].y) * vv[k]);
    }
    __syncthreads();
    if (t < BINW) {
        int node = b * BINW + t;
        if (node < n) {
            double S = acc[0][t] + acc[1][t] + acc[2][t] + acc[3][t];
            double di = (double)disA[node];
            v2[node] = di * (tpart[node] + di * S);
        }
    }
}

// same structure: acc[sub][dlow] += ew * v2[s]; u = c0 + dis*(v2 + S)
__global__ __launch_bounds__(512) void spmv2_head_kernel(
        const uint2* __restrict__ binned, const unsigned* __restrict__ binBase,
        const double* __restrict__ v2, const float* __restrict__ disA,
        const double* __restrict__ cvals, float* __restrict__ out, int n) {
    __shared__ double acc[4][BINW];
    const int b = blockIdx.x;
    const int t = threadIdx.x;
    const int sub = t >> 7;
    {
        double* f = &acc[0][0];
        if (t < 512) f[t] = 0.0;
    }
    __syncthreads();
    const unsigned s0 = binBase[b], s1 = binBase[b + 1];
    for (unsigned tile = s0; tile < s1; tile += 2048) {
        uint2 ee[4];
        double vv[4];
        bool ok[4];
#pragma unroll
        for (int k = 0; k < 4; k++) {
            unsigned idx = tile + t + k * 512u;
            ok[k] = (idx < s1);
            if (ok[k]) ee[k] = binned[idx];
        }
#pragma unroll
        for (int k = 0; k < 4; k++)
            if (ok[k]) vv[k] = v2[ee[k].x & 0xFFFFFu];
#pragma unroll
        for (int k = 0; k < 4; k++)
            if (ok[k])
                atomicAdd(&acc[sub][ee[k].x >> 20],
                          (double)__uint_as_float(ee[k].y) * vv[k]);
    }
    __syncthreads();
    if (t < BINW) {
        int node = b * BINW + t;
        if (node < n) {
            double S = acc[0][t] + acc[1][t] + acc[2][t] + acc[3][t];
            double u = cvals[0] + (double)disA[node] * (v2[node] + S);
            float o = (float)u;
            o = fminf(fmaxf(o, 0.0f), 10.0f);
            out[node] = rintf(o);  // v_rndne_f32: half-to-even, matches jnp.round
        }
    }
}

extern "C" void kernel_launch(void* const* d_in, const int* in_sizes, int n_in,
                              void* d_out, int out_size, void* d_ws, size_t ws_size,
                              hipStream_t stream) {
    const float* x   = (const float*)d_in[0];  // [N, 128]
    const int*   eix = (const int*)d_in[1];    // [2, E]
    const float* ew  = (const float*)d_in[2];  // [E]
    const float* W1  = (const float*)d_in[3];  // [128, 64]
    const float* b1  = (const float*)d_in[4];  // [64]
    const float* W2  = (const float*)d_in[5];  // [64, 64]
    const float* b2  = (const float*)d_in[6];  // [64]
    const float* fcw = (const float*)d_in[7];  // [64]
    const float* fcb = (const float*)d_in[8];  // [1]
    float* out = (float*)d_out;                // [N]

    const int n = in_sizes[0] / DIN;
    const int e = in_sizes[2];
    const int* src = eix;
    const int* dst = eix + e;
    const int nb = (n + BINW - 1) / BINW;            // 782 bins at n=100000
    const int hblk = (e + CHUNK - 1) / CHUNK;        // 196 chunks

    // workspace layout (8-byte units, 64-unit aligned regions); ~18 MB
    auto al = [](size_t v) { return (v + 63) & ~(size_t)63; };
    double* ws = (double*)d_ws;
    size_t o = 0;
    double*   w1f     = ws + o; o += al(DIN);
    double*   cvals   = ws + o; o += al(2);
    double*   q       = ws + o; o += al((size_t)n);
    double*   tpart   = ws + o; o += al((size_t)n);
    double*   v1      = ws + o; o += al((size_t)n);
    double*   v2      = ws + o; o += al((size_t)n);
    float*    disA    = (float*)(ws + o);    o += al(((size_t)n + 1) / 2);
    unsigned* binCnt  = (unsigned*)(ws + o); o += al(((size_t)nb + 1) / 2);
    unsigned* binBase = (unsigned*)(ws + o); o += al(((size_t)nb + 2) / 2);
    unsigned* histT   = (unsigned*)(ws + o); o += al(((size_t)nb * hblk + 1) / 2);
    unsigned* chunkOfsT = (unsigned*)(ws + o); o += al(((size_t)nb * hblk + 1) / 2);
    uint2*    binned  = (uint2*)(ws + o);   // e * 8B = 12.8 MB

    const int gemvblk = (n + 7) / 8;                 // 2 rows/wave, 4 waves/block
    const int bsblk = (nb * 64 + 255) / 256;         // binscan: wave per bin

    precompute_kernel<<<1, 256, 0, stream>>>(W1, b1, W2, b2, fcw, fcb, w1f, cvals);
    hist_gemv_kernel<<<hblk + gemvblk, 256, 0, stream>>>(dst, x, w1f, histT,
                                                         q, n, e, nb, hblk);
    binscan_kernel<<<bsblk, 256, 0, stream>>>(histT, chunkOfsT, binCnt, nb, hblk);
    scan_kernel<<<1, 256, 0, stream>>>(binCnt, binBase, nb);
    binscatter_kernel<<<hblk, 1024, 0, stream>>>(src, dst, ew, binBase, chunkOfsT,
                                                 binned, e, nb);
    setup_kernel<<<nb, 256, 0, stream>>>(binned, binBase, cvals, q, disA, v1,
                                         tpart, n);
    spmv1_kernel<<<nb, 512, 0, stream>>>(binned, binBase, v1, disA, tpart, v2, n);
    spmv2_head_kernel<<<nb, 512, 0, stream>>>(binned, binBase, v2, disA, cvals,
                                              out, n);
}